// Round 4
// baseline (776.721 us; speedup 1.0000x reference)
//
#include <hip/hip_runtime.h>

// ---------------- problem constants ----------------
#define VOCAB 18
#define EMB   200
#define HID   200
#define G4    800           // 4*HID
#define SEQ   128
#define BATCH 2048
#define MB    8             // batch rows per block
#define NT    56            // N tiles of 16: 50 gate tiles + 2 W_out tiles + 4 zero
#define KS    7             // K steps of 32 -> 224 padded K
#define TPB   512           // 8 waves
#define TPW   7             // tiles per wave (56/8)
#define LOGITS_N ((size_t)BATCH*SEQ*VOCAB)

typedef short s16x8 __attribute__((ext_vector_type(8)));
typedef float f32x4 __attribute__((ext_vector_type(4)));

__device__ __forceinline__ unsigned short f2bf(float f) {
  unsigned int u = __float_as_uint(f);
  u += 0x7FFFu + ((u >> 16) & 1u);            // RNE; no NaNs in this problem
  return (unsigned short)(u >> 16);
}
__device__ __forceinline__ float bf2f(unsigned short s) {
  return __uint_as_float(((unsigned int)s) << 16);
}
__device__ __forceinline__ float sigm(float x) {
  float e = __builtin_amdgcn_exp2f(x * 1.4426950408889634f);
  return e * __builtin_amdgcn_rcpf(e + 1.0f);
}
__device__ __forceinline__ float tanhq(float x) {
  float e = __builtin_amdgcn_exp2f(x * 2.8853900817779268f); // exp2(2x*log2e)
  return 1.0f - 2.0f * __builtin_amdgcn_rcpf(e + 1.0f);
}

// ---------------- prep (unchanged) ----------------
// tbl[v][j] = (v!=0)*dot(E[v], W_ih[j]) + b_ih[j] + b_hh[j], bf16, 18x800.
// Wp: 56 tiles x 7 K-steps, B-frag order: lane l elem i = B[32s+8*(l>>4)+i][16n+(l&15)]
//   B[k][col] = W_hh[col][k] (col<800), W_out[col-800][k] (800<=col<818), else 0.
__global__ void prep_kernel(const float* __restrict__ E, const float* __restrict__ W_ih,
                            const float* __restrict__ W_hh, const float* __restrict__ b_ih,
                            const float* __restrict__ b_hh, const float* __restrict__ W_out,
                            unsigned short* __restrict__ tbl, short* __restrict__ Wp) {
  int tid = blockIdx.x * 256 + threadIdx.x;
  if (tid < VOCAB * G4) {
    int v = tid / G4, col = tid % G4;
    float s = b_ih[col] + b_hh[col];
    if (v != 0) {
      const float* Er = E + v * EMB;
      const float* Wr = W_ih + col * EMB;
      for (int e = 0; e < EMB; ++e) s += Er[e] * Wr[e];
    }
    tbl[tid] = f2bf(s);
  } else if (tid < VOCAB*G4 + NT*KS*64) {
    int u = tid - VOCAB*G4;
    int n    = u / (KS*64);
    int rem  = u % (KS*64);
    int s_   = rem >> 6;
    int lane = rem & 63;
    int col  = 16*n + (lane & 15);
    int kb   = lane >> 4;
    s16x8 o;
    #pragma unroll
    for (int i = 0; i < 8; ++i) {
      int k = 32*s_ + 8*kb + i;
      float f = 0.f;
      if (k < HID) {
        if (col < G4)            f = W_hh[col*HID + k];
        else if (col < G4+VOCAB) f = W_out[(col-G4)*HID + k];
      }
      o[i] = (short)f2bf(f);
    }
    *(s16x8*)(Wp + (size_t)u * 8) = o;
  }
}

// ---------------- main: weights pinned to AGPRs (opaque defs, no remat);
// MFMA via BUILTIN so the compiler inserts the required hazard nops.
// Phase A split into two N-groups to keep acc live-range at 16 regs. --------
__global__ __launch_bounds__(TPB, 2)
void lstm_kernel(const int* __restrict__ x, const unsigned short* __restrict__ tbl,
                 const short* __restrict__ Wp, const float* __restrict__ b_out,
                 float* __restrict__ out) {
  __shared__ unsigned short hA[KS*64*8];       // h in A-frag layout, bf16 (7.2KB)
  __shared__ float gatesL[MB*G4];              // 25.6KB
  __shared__ int   xtok[MB*SEQ];               // 4KB

  const int tid  = threadIdx.x;
  const int lane = tid & 63;
  const int w    = tid >> 6;                   // wave 0..7
  const int blk  = blockIdx.x;
  const int l15  = lane & 15;
  const int rowq = (lane >> 4) << 2;           // C rows rowq..rowq+3 (lanes<32 real)
  const bool lo  = (lane < 32);

  for (int i = tid; i < KS*64*8; i += TPB) hA[i] = 0;      // h0 = 0 (+pad rows)
  for (int i = tid; i < MB*SEQ;  i += TPB) xtok[i] = x[blk*(MB*SEQ) + i];

  // resident weight fragments: 49 x 4 regs, pinned into AGPRs once.
  // Opaque asm def -> compiler cannot re-load them from Wp inside the t-loop.
  s16x8 wf[TPW][KS];
  #pragma unroll
  for (int n = 0; n < TPW; ++n) {
    #pragma unroll
    for (int s = 0; s < KS; ++s) {
      wf[n][s] = *(const s16x8*)(Wp + ((((w*TPW + n)*KS) + s)*64 + lane) * 8);
      asm volatile("" : "+a"(wf[n][s]));
    }
  }

  // b_out for the two logits tiles (only wave 7 uses)
  const float bo1 = (l15 < VOCAB)      ? b_out[l15]      : 0.f;
  const float bo2 = (16 + l15 < VOCAB) ? b_out[16 + l15] : 0.f;

  float creg[4] = {0.f, 0.f, 0.f, 0.f};        // c state, thread-resident

  __syncthreads();

  for (int t = 0; t < SEQ; ++t) {
    // ---- phase A: MFMA sweep in two N-groups -> gates + logits(t-1) ----
    auto store_tile = [&](int n, const f32x4& a) {
      int col = 16*(w*TPW + n) + l15;
      if (col < G4) {
        #pragma unroll
        for (int q = 0; q < 4; ++q)
          gatesL[(rowq + q)*G4 + col] = a[q];
      } else if (col < G4 + 32 && t > 0) {     // logits for step t-1
        int v = col - G4;
        if (v < VOCAB) {
          float bo = (v < 16) ? bo1 : bo2;
          #pragma unroll
          for (int q = 0; q < 4; ++q) {
            size_t bg = (size_t)blk*MB + rowq + q;
            out[(bg*SEQ + (t-1))*VOCAB + v] = a[q] + bo;
          }
        }
      }
    };

    {   // group 0: tiles n = 0..3
      f32x4 acc[4];
      #pragma unroll
      for (int n = 0; n < 4; ++n) { acc[n][0]=0.f; acc[n][1]=0.f; acc[n][2]=0.f; acc[n][3]=0.f; }
      #pragma unroll
      for (int s = 0; s < KS; ++s) {
        s16x8 aF = *(const s16x8*)&hA[(s*64 + lane)*8];
        #pragma unroll
        for (int n = 0; n < 4; ++n)
          acc[n] = __builtin_amdgcn_mfma_f32_16x16x32_bf16(aF, wf[n][s], acc[n], 0, 0, 0);
      }
      if (lo) { store_tile(0, acc[0]); store_tile(1, acc[1]); store_tile(2, acc[2]); store_tile(3, acc[3]); }
    }
    {   // group 1: tiles n = 4..6
      f32x4 acc[3];
      #pragma unroll
      for (int n = 0; n < 3; ++n) { acc[n][0]=0.f; acc[n][1]=0.f; acc[n][2]=0.f; acc[n][3]=0.f; }
      #pragma unroll
      for (int s = 0; s < KS; ++s) {
        s16x8 aF = *(const s16x8*)&hA[(s*64 + lane)*8];
        #pragma unroll
        for (int n = 0; n < 3; ++n)
          acc[n] = __builtin_amdgcn_mfma_f32_16x16x32_bf16(aF, wf[4+n][s], acc[n], 0, 0, 0);
      }
      if (lo) { store_tile(4, acc[0]); store_tile(5, acc[1]); store_tile(6, acc[2]); }
    }
    __syncthreads();

    // ---- phase B: + table gather, activations, c/h update, h -> hA ----
    #pragma unroll
    for (int it = 0; it < 4; ++it) {
      int p = tid + TPB*it;
      if (p < MB*HID) {
        int r = p / HID;
        int j = p - r*HID;
        int v = xtok[r*SEQ + t];
        const unsigned short* tr = tbl + v*G4 + j;
        float xi = gatesL[r*G4 + j]       + bf2f(tr[0]);
        float xf = gatesL[r*G4 + j + 200] + bf2f(tr[200]);
        float xg = gatesL[r*G4 + j + 400] + bf2f(tr[400]);
        float xo = gatesL[r*G4 + j + 600] + bf2f(tr[600]);
        float i_ = sigm(xi);
        float f_ = sigm(xf);
        float g_ = tanhq(xg);
        float o_ = sigm(xo);
        float cn = f_*creg[it] + i_*g_;
        float h  = o_*tanhq(cn);
        creg[it] = cn;
        hA[((j>>5)*64 + (r + 16*((j>>3)&3)))*8 + (j&7)] = f2bf(h);
        if (t == SEQ-1) {
          size_t bg = (size_t)blk*MB + r;
          out[LOGITS_N + bg*HID + j] = h;                          // h_n
          out[LOGITS_N + (size_t)BATCH*HID + bg*HID + j] = cn;     // c_n
        }
      }
    }
    __syncthreads();
  }

  // ---- epilogue: logits for t = SEQ-1 from final h (wave 7's tiles 50/51) ----
  if (w == 7) {
    f32x4 a1, a2;
    a1[0]=0.f; a1[1]=0.f; a1[2]=0.f; a1[3]=0.f;
    a2[0]=0.f; a2[1]=0.f; a2[2]=0.f; a2[3]=0.f;
    #pragma unroll
    for (int s = 0; s < KS; ++s) {
      s16x8 aF = *(const s16x8*)&hA[(s*64 + lane)*8];
      a1 = __builtin_amdgcn_mfma_f32_16x16x32_bf16(aF, wf[1][s], a1, 0, 0, 0);
      a2 = __builtin_amdgcn_mfma_f32_16x16x32_bf16(aF, wf[2][s], a2, 0, 0, 0);
    }
    if (lo) {
      #pragma unroll
      for (int q = 0; q < 4; ++q) {
        size_t bg = (size_t)blk*MB + rowq + q;
        size_t base = (bg*SEQ + (SEQ-1))*VOCAB;
        if (l15 < VOCAB)      out[base + l15]      = a1[q] + bo1;
        if (16 + l15 < VOCAB) out[base + 16 + l15] = a2[q] + bo2;
      }
    }
  }
}

extern "C" void kernel_launch(void* const* d_in, const int* in_sizes, int n_in,
                              void* d_out, int out_size, void* d_ws, size_t ws_size,
                              hipStream_t stream) {
  const int*   x     = (const int*)  d_in[0];
  const float* E     = (const float*)d_in[1];
  const float* W_ih  = (const float*)d_in[2];
  const float* W_hh  = (const float*)d_in[3];
  const float* b_ih  = (const float*)d_in[4];
  const float* b_hh  = (const float*)d_in[5];
  const float* W_out = (const float*)d_in[6];
  const float* b_out = (const float*)d_in[7];
  float* out = (float*)d_out;

  // ws layout: tbl 18*800*2 = 28800B | Wp 56*7*64*8*2 = 401408B   (~430KB)
  unsigned short* tbl = (unsigned short*)d_ws;
  short* Wp = (short*)d_ws + VOCAB*G4;

  int prep_threads = VOCAB*G4 + NT*KS*64;
  int prep_blocks  = (prep_threads + 255) / 256;
  prep_kernel<<<prep_blocks, 256, 0, stream>>>(E, W_ih, W_hh, b_ih, b_hh, W_out,
                                               tbl, Wp);
  lstm_kernel<<<BATCH/MB, TPB, 0, stream>>>(x, tbl, Wp, b_out, out);
}

// Round 5
// 712.538 us; speedup vs baseline: 1.0901x; 1.0901x over previous
//
#include <hip/hip_runtime.h>

// ---------------- problem constants ----------------
#define VOCAB 18
#define EMB   200
#define HID   200
#define G4    800           // 4*HID
#define SEQ   128
#define BATCH 2048
#define MB    8             // batch rows per block
#define NT    56            // N tiles of 16: 50 gate tiles + 2 W_out tiles + 4 zero
#define KS    7             // K steps of 32 -> 224 padded K
#define TPB   512           // 8 waves
#define TPW   7             // tiles per wave (56/8)
#define LOGITS_N ((size_t)BATCH*SEQ*VOCAB)

typedef short s16x8 __attribute__((ext_vector_type(8)));
typedef float f32x4 __attribute__((ext_vector_type(4)));

__device__ __forceinline__ unsigned short f2bf(float f) {
  unsigned int u = __float_as_uint(f);
  u += 0x7FFFu + ((u >> 16) & 1u);            // RNE; no NaNs in this problem
  return (unsigned short)(u >> 16);
}
__device__ __forceinline__ float bf2f(unsigned short s) {
  return __uint_as_float(((unsigned int)s) << 16);
}
__device__ __forceinline__ float sigm(float x) {
  float e = __builtin_amdgcn_exp2f(x * 1.4426950408889634f);
  return e * __builtin_amdgcn_rcpf(e + 1.0f);
}
__device__ __forceinline__ float tanhq(float x) {
  float e = __builtin_amdgcn_exp2f(x * 2.8853900817779268f); // exp2(2x*log2e)
  return 1.0f - 2.0f * __builtin_amdgcn_rcpf(e + 1.0f);
}

// ---------------- prep (unchanged) ----------------
// tbl[v][j] = (v!=0)*dot(E[v], W_ih[j]) + b_ih[j] + b_hh[j], bf16, 18x800.
// Wp: 56 tiles x 7 K-steps, B-frag order: lane l elem i = B[32s+8*(l>>4)+i][16n+(l&15)]
//   B[k][col] = W_hh[col][k] (col<800), W_out[col-800][k] (800<=col<818), else 0.
__global__ void prep_kernel(const float* __restrict__ E, const float* __restrict__ W_ih,
                            const float* __restrict__ W_hh, const float* __restrict__ b_ih,
                            const float* __restrict__ b_hh, const float* __restrict__ W_out,
                            unsigned short* __restrict__ tbl, short* __restrict__ Wp) {
  int tid = blockIdx.x * 256 + threadIdx.x;
  if (tid < VOCAB * G4) {
    int v = tid / G4, col = tid % G4;
    float s = b_ih[col] + b_hh[col];
    if (v != 0) {
      const float* Er = E + v * EMB;
      const float* Wr = W_ih + col * EMB;
      for (int e = 0; e < EMB; ++e) s += Er[e] * Wr[e];
    }
    tbl[tid] = f2bf(s);
  } else if (tid < VOCAB*G4 + NT*KS*64) {
    int u = tid - VOCAB*G4;
    int n    = u / (KS*64);
    int rem  = u % (KS*64);
    int s_   = rem >> 6;
    int lane = rem & 63;
    int col  = 16*n + (lane & 15);
    int kb   = lane >> 4;
    s16x8 o;
    #pragma unroll
    for (int i = 0; i < 8; ++i) {
      int k = 32*s_ + 8*kb + i;
      float f = 0.f;
      if (k < HID) {
        if (col < G4)            f = W_hh[col*HID + k];
        else if (col < G4+VOCAB) f = W_out[(col-G4)*HID + k];
      }
      o[i] = (short)f2bf(f);
    }
    *(s16x8*)(Wp + (size_t)u * 8) = o;
  }
}

// ---------------- main ----------------
// amdgpu_waves_per_eu(2,2): occupancy pinned at 2 waves/EU -> full 256-reg
// unified budget per wave. Weights (196 regs) pinned to AGPRs; builtins for
// MFMA (compiler handles hazards). Phase A split in two N-groups keeps the
// arch-VGPR live set small so accum_offset stays low (AGPR partition >= 196).
__global__ __launch_bounds__(TPB) __attribute__((amdgpu_waves_per_eu(2, 2)))
void lstm_kernel(const int* __restrict__ x, const unsigned short* __restrict__ tbl,
                 const short* __restrict__ Wp, const float* __restrict__ b_out,
                 float* __restrict__ out) {
  __shared__ unsigned short hA[KS*64*8];       // h in A-frag layout, bf16 (7.2KB)
  __shared__ float gatesL[MB*G4];              // 25.6KB
  __shared__ int   xtok[MB*SEQ];               // 4KB
  __shared__ unsigned short tblL[VOCAB*G4];    // 28.8KB

  const int tid  = threadIdx.x;
  const int lane = tid & 63;
  const int w    = tid >> 6;                   // wave 0..7
  const int blk  = blockIdx.x;
  const int l15  = lane & 15;
  const int rowq = (lane >> 4) << 2;           // C rows rowq..rowq+3 (lanes<32 real)
  const bool lo  = (lane < 32);

  for (int i = tid; i < KS*64*8; i += TPB) hA[i] = 0;      // h0 = 0 (+pad rows)
  for (int i = tid; i < MB*SEQ;  i += TPB) xtok[i] = x[blk*(MB*SEQ) + i];
  for (int i = tid; i < VOCAB*G4; i += TPB) tblL[i] = tbl[i];

  // resident weight fragments: 49 x 4 regs, pinned into AGPRs once.
  s16x8 wf[TPW][KS];
  #pragma unroll
  for (int n = 0; n < TPW; ++n) {
    #pragma unroll
    for (int s = 0; s < KS; ++s) {
      wf[n][s] = *(const s16x8*)(Wp + ((((w*TPW + n)*KS) + s)*64 + lane) * 8);
      asm volatile("" : "+a"(wf[n][s]));
    }
  }

  // b_out for the two logits tiles (only wave 7 uses)
  const float bo1 = (l15 < VOCAB)      ? b_out[l15]      : 0.f;
  const float bo2 = (16 + l15 < VOCAB) ? b_out[16 + l15] : 0.f;

  float creg[4] = {0.f, 0.f, 0.f, 0.f};        // c state, thread-resident

  __syncthreads();

  #pragma unroll 1
  for (int t = 0; t < SEQ; ++t) {
    // ---- phase A: MFMA sweep in two N-groups -> gates + logits(t-1) ----
    auto store_tile = [&](int n, const f32x4& a) {
      int col = 16*(w*TPW + n) + l15;
      if (col < G4) {
        #pragma unroll
        for (int q = 0; q < 4; ++q)
          gatesL[(rowq + q)*G4 + col] = a[q];
      } else if (col < G4 + 32 && t > 0) {     // logits for step t-1
        int v = col - G4;
        if (v < VOCAB) {
          float bo = (v < 16) ? bo1 : bo2;
          #pragma unroll
          for (int q = 0; q < 4; ++q) {
            size_t bg = (size_t)blk*MB + rowq + q;
            out[(bg*SEQ + (t-1))*VOCAB + v] = a[q] + bo;
          }
        }
      }
    };

    {   // group 0: tiles n = 0..3
      f32x4 acc[4];
      #pragma unroll
      for (int n = 0; n < 4; ++n) { acc[n][0]=0.f; acc[n][1]=0.f; acc[n][2]=0.f; acc[n][3]=0.f; }
      #pragma unroll
      for (int s = 0; s < KS; ++s) {
        s16x8 aF = *(const s16x8*)&hA[(s*64 + lane)*8];
        #pragma unroll
        for (int n = 0; n < 4; ++n)
          acc[n] = __builtin_amdgcn_mfma_f32_16x16x32_bf16(aF, wf[n][s], acc[n], 0, 0, 0);
      }
      if (lo) { store_tile(0, acc[0]); store_tile(1, acc[1]); store_tile(2, acc[2]); store_tile(3, acc[3]); }
    }
    {   // group 1: tiles n = 4..6
      f32x4 acc[3];
      #pragma unroll
      for (int n = 0; n < 3; ++n) { acc[n][0]=0.f; acc[n][1]=0.f; acc[n][2]=0.f; acc[n][3]=0.f; }
      #pragma unroll
      for (int s = 0; s < KS; ++s) {
        s16x8 aF = *(const s16x8*)&hA[(s*64 + lane)*8];
        #pragma unroll
        for (int n = 0; n < 3; ++n)
          acc[n] = __builtin_amdgcn_mfma_f32_16x16x32_bf16(aF, wf[4+n][s], acc[n], 0, 0, 0);
      }
      if (lo) { store_tile(4, acc[0]); store_tile(5, acc[1]); store_tile(6, acc[2]); }
    }
    __syncthreads();

    // ---- phase B: + table gather (LDS), activations, c/h update, h -> hA ----
    #pragma unroll
    for (int it = 0; it < 4; ++it) {
      int p = tid + TPB*it;
      if (p < MB*HID) {
        int r = p / HID;
        int j = p - r*HID;
        int v = xtok[r*SEQ + t];
        const unsigned short* tr = tblL + v*G4 + j;
        float xi = gatesL[r*G4 + j]       + bf2f(tr[0]);
        float xf = gatesL[r*G4 + j + 200] + bf2f(tr[200]);
        float xg = gatesL[r*G4 + j + 400] + bf2f(tr[400]);
        float xo = gatesL[r*G4 + j + 600] + bf2f(tr[600]);
        float i_ = sigm(xi);
        float f_ = sigm(xf);
        float g_ = tanhq(xg);
        float o_ = sigm(xo);
        float cn = f_*creg[it] + i_*g_;
        float h  = o_*tanhq(cn);
        creg[it] = cn;
        hA[((j>>5)*64 + (r + 16*((j>>3)&3)))*8 + (j&7)] = f2bf(h);
        if (t == SEQ-1) {
          size_t bg = (size_t)blk*MB + r;
          out[LOGITS_N + bg*HID + j] = h;                          // h_n
          out[LOGITS_N + (size_t)BATCH*HID + bg*HID + j] = cn;     // c_n
        }
      }
    }
    __syncthreads();
  }

  // ---- epilogue: logits for t = SEQ-1 from final h (wave 7's tiles 50/51) ----
  if (w == 7) {
    f32x4 a1, a2;
    a1[0]=0.f; a1[1]=0.f; a1[2]=0.f; a1[3]=0.f;
    a2[0]=0.f; a2[1]=0.f; a2[2]=0.f; a2[3]=0.f;
    #pragma unroll
    for (int s = 0; s < KS; ++s) {
      s16x8 aF = *(const s16x8*)&hA[(s*64 + lane)*8];
      a1 = __builtin_amdgcn_mfma_f32_16x16x32_bf16(aF, wf[1][s], a1, 0, 0, 0);
      a2 = __builtin_amdgcn_mfma_f32_16x16x32_bf16(aF, wf[2][s], a2, 0, 0, 0);
    }
    if (lo) {
      #pragma unroll
      for (int q = 0; q < 4; ++q) {
        size_t bg = (size_t)blk*MB + rowq + q;
        size_t base = (bg*SEQ + (SEQ-1))*VOCAB;
        if (l15 < VOCAB)      out[base + l15]      = a1[q] + bo1;
        if (16 + l15 < VOCAB) out[base + 16 + l15] = a2[q] + bo2;
      }
    }
  }
}

extern "C" void kernel_launch(void* const* d_in, const int* in_sizes, int n_in,
                              void* d_out, int out_size, void* d_ws, size_t ws_size,
                              hipStream_t stream) {
  const int*   x     = (const int*)  d_in[0];
  const float* E     = (const float*)d_in[1];
  const float* W_ih  = (const float*)d_in[2];
  const float* W_hh  = (const float*)d_in[3];
  const float* b_ih  = (const float*)d_in[4];
  const float* b_hh  = (const float*)d_in[5];
  const float* W_out = (const float*)d_in[6];
  const float* b_out = (const float*)d_in[7];
  float* out = (float*)d_out;

  // ws layout: tbl 18*800*2 = 28800B | Wp 56*7*64*8*2 = 401408B   (~430KB)
  unsigned short* tbl = (unsigned short*)d_ws;
  short* Wp = (short*)d_ws + VOCAB*G4;

  int prep_threads = VOCAB*G4 + NT*KS*64;
  int prep_blocks  = (prep_threads + 255) / 256;
  prep_kernel<<<prep_blocks, 256, 0, stream>>>(E, W_ih, W_hh, b_ih, b_hh, W_out,
                                               tbl, Wp);
  lstm_kernel<<<BATCH/MB, TPB, 0, stream>>>(x, tbl, Wp, b_out, out);
}

// Round 6
// 466.773 us; speedup vs baseline: 1.6640x; 1.5265x over previous
//
#include <hip/hip_runtime.h>

// ---------------- problem constants ----------------
#define VOCAB 18
#define EMB   200
#define HID   200
#define G4    800           // 4*HID
#define SEQ   128
#define BATCH 2048
#define MB    8             // batch rows per block
#define NT    56            // N tiles of 16: 50 gate tiles + 2 logit tiles + 4 zero
#define KS    7             // K steps of 32 -> 224 padded K (k=200 row = logit bias)
#define TPB   256           // 4 waves -> 1 wave/SIMD -> 512-reg budget [m08]
#define TPW   14            // tiles per wave (56/4)
#define LOGITS_N ((size_t)BATCH*SEQ*VOCAB)

typedef short s16x8 __attribute__((ext_vector_type(8)));
typedef float f32x4 __attribute__((ext_vector_type(4)));

__device__ __forceinline__ unsigned short f2bf(float f) {
  unsigned int u = __float_as_uint(f);
  u += 0x7FFFu + ((u >> 16) & 1u);            // RNE; no NaNs in this problem
  return (unsigned short)(u >> 16);
}
__device__ __forceinline__ float bf2f(unsigned short s) {
  return __uint_as_float(((unsigned int)s) << 16);
}
__device__ __forceinline__ float sigm(float x) {
  float e = __builtin_amdgcn_exp2f(x * 1.4426950408889634f);
  return e * __builtin_amdgcn_rcpf(e + 1.0f);
}
__device__ __forceinline__ float tanhq(float x) {
  float e = __builtin_amdgcn_exp2f(x * 2.8853900817779268f); // exp2(2x*log2e)
  return 1.0f - 2.0f * __builtin_amdgcn_rcpf(e + 1.0f);
}

// ---------------- prep ----------------
// tbl[v][j] = (v!=0)*dot(E[v], W_ih[j]) + b_ih[j] + b_hh[j], bf16, 18x800.
// Wp: 56 tiles x 7 K-steps, B-frag order: lane l elem i = B[32s+8*(l>>4)+i][16n+(l&15)]
//   B[k][col] = W_hh[col][k]          (col<800, k<200)
//             = W_out[col-800][k]     (800<=col<818, k<200)
//             = b_out[col-800]        (800<=col<818, k==200)  <- bias row
//             = 0 otherwise
__global__ void prep_kernel(const float* __restrict__ E, const float* __restrict__ W_ih,
                            const float* __restrict__ W_hh, const float* __restrict__ b_ih,
                            const float* __restrict__ b_hh, const float* __restrict__ W_out,
                            const float* __restrict__ b_out,
                            unsigned short* __restrict__ tbl, short* __restrict__ Wp) {
  int tid = blockIdx.x * 256 + threadIdx.x;
  if (tid < VOCAB * G4) {
    int v = tid / G4, col = tid % G4;
    float s = b_ih[col] + b_hh[col];
    if (v != 0) {
      const float* Er = E + v * EMB;
      const float* Wr = W_ih + col * EMB;
      for (int e = 0; e < EMB; ++e) s += Er[e] * Wr[e];
    }
    tbl[tid] = f2bf(s);
  } else if (tid < VOCAB*G4 + NT*KS*64) {
    int u = tid - VOCAB*G4;
    int n    = u / (KS*64);
    int rem  = u % (KS*64);
    int s_   = rem >> 6;
    int lane = rem & 63;
    int col  = 16*n + (lane & 15);
    int kb   = lane >> 4;
    s16x8 o;
    #pragma unroll
    for (int i = 0; i < 8; ++i) {
      int k = 32*s_ + 8*kb + i;
      float f = 0.f;
      if (col < G4) {
        if (k < HID) f = W_hh[col*HID + k];
      } else if (col < G4+VOCAB) {
        if (k < HID)       f = W_out[(col-G4)*HID + k];
        else if (k == HID) f = b_out[col-G4];          // bias row (k=200)
      }
      o[i] = (short)f2bf(f);
    }
    *(s16x8*)(Wp + (size_t)u * 8) = o;
  }
}

// ---------------- main ----------------
// 256 blocks x 8 batch rows; 4 waves (1/SIMD) -> 512-reg/wave budget.
// Each wave holds 14 weight tiles x 7 K-steps = 392 AGPRs, pinned once.
// Prologue loads are fenced every 7 frags to bound in-flight arch VGPRs.
// Phase A: tiles in groups of 4 (4 indep MFMA chains, acc live = 16 regs).
// Logit bias comes free via the k=200 bias row x hA's planted 1.0.
__global__ __launch_bounds__(TPB) __attribute__((amdgpu_waves_per_eu(1, 1)))
void lstm_kernel(const int* __restrict__ x, const unsigned short* __restrict__ tbl,
                 const short* __restrict__ Wp, float* __restrict__ out) {
  __shared__ unsigned short hA[KS*64*8];       // h in A-frag layout, bf16 (7.2KB)
  __shared__ float gatesL[MB*G4];              // 25.6KB
  __shared__ int   xtok[MB*SEQ];               // 4KB
  __shared__ unsigned short tblL[VOCAB*G4];    // 28.8KB

  const int tid  = threadIdx.x;
  const int lane = tid & 63;
  const int w    = tid >> 6;                   // wave 0..3
  const int blk  = blockIdx.x;
  const int l15  = lane & 15;
  const int rowq = (lane >> 4) << 2;           // C rows rowq..rowq+3 (lanes<32 real)
  const bool lo  = (lane < 32);

  // h0 = 0 everywhere except bf16 1.0 at k=200 (bias slot): idx (400+r)*8, r=0..7
  for (int i = tid; i < KS*64*8; i += TPB)
    hA[i] = (i >= 3200 && i < 3264 && (i & 7) == 0) ? (unsigned short)0x3F80
                                                    : (unsigned short)0;
  for (int i = tid; i < MB*SEQ; i += TPB) xtok[i] = x[blk*(MB*SEQ) + i];
  for (int i = tid; i < VOCAB*G4/8; i += TPB)
    ((s16x8*)tblL)[i] = ((const s16x8*)tbl)[i];

  // resident weight fragments: 14 tiles x 7 steps x 4 regs = 392 AGPRs, pinned.
  // memory-clobber fence per tile bounds in-flight loads to 7 frags (28 regs).
  s16x8 wf[TPW][KS];
  #pragma unroll
  for (int n = 0; n < TPW; ++n) {
    #pragma unroll
    for (int s = 0; s < KS; ++s) {
      wf[n][s] = *(const s16x8*)(Wp + ((((w*TPW + n)*KS) + s)*64 + lane) * 8);
      asm volatile("" : "+a"(wf[n][s]));
    }
    asm volatile("" ::: "memory");
  }

  float creg[7] = {0.f, 0.f, 0.f, 0.f, 0.f, 0.f, 0.f};   // c state, thread-resident

  __syncthreads();

  #pragma unroll 1
  for (int t = 0; t < SEQ; ++t) {
    // ---- phase A: MFMA sweep, groups of 4 tiles -> gates + logits(t-1) ----
    auto store_tile = [&](int n, const f32x4& a) {
      int col = 16*(w*TPW + n) + l15;
      if (col < G4) {
        #pragma unroll
        for (int q = 0; q < 4; ++q)
          gatesL[(rowq + q)*G4 + col] = a[q];
      } else if (col < G4 + 32 && t > 0) {     // logits for step t-1 (bias baked in)
        int v = col - G4;
        if (v < VOCAB) {
          #pragma unroll
          for (int q = 0; q < 4; ++q) {
            size_t bg = (size_t)blk*MB + rowq + q;
            out[(bg*SEQ + (t-1))*VOCAB + v] = a[q];
          }
        }
      }
    };

    #pragma unroll
    for (int g = 0; g < 4; ++g) {
      f32x4 acc[4];
      #pragma unroll
      for (int j = 0; j < 4; ++j) { acc[j][0]=0.f; acc[j][1]=0.f; acc[j][2]=0.f; acc[j][3]=0.f; }
      #pragma unroll
      for (int s = 0; s < KS; ++s) {
        s16x8 aF = *(const s16x8*)&hA[(s*64 + lane)*8];
        #pragma unroll
        for (int j = 0; j < 4; ++j)
          if (4*g + j < TPW)
            acc[j] = __builtin_amdgcn_mfma_f32_16x16x32_bf16(aF, wf[4*g + j][s], acc[j], 0, 0, 0);
      }
      if (lo) {
        #pragma unroll
        for (int j = 0; j < 4; ++j)
          if (4*g + j < TPW) store_tile(4*g + j, acc[j]);
      }
    }
    __syncthreads();

    // ---- phase B: + table gather (LDS), activations, c/h update, h -> hA ----
    #pragma unroll
    for (int it = 0; it < 7; ++it) {
      int p = tid + TPB*it;
      if (p < MB*HID) {
        int r = p / HID;
        int j = p - r*HID;
        int v = xtok[r*SEQ + t];
        const unsigned short* tr = tblL + v*G4 + j;
        float xi = gatesL[r*G4 + j]       + bf2f(tr[0]);
        float xf = gatesL[r*G4 + j + 200] + bf2f(tr[200]);
        float xg = gatesL[r*G4 + j + 400] + bf2f(tr[400]);
        float xo = gatesL[r*G4 + j + 600] + bf2f(tr[600]);
        float i_ = sigm(xi);
        float f_ = sigm(xf);
        float g_ = tanhq(xg);
        float o_ = sigm(xo);
        float cn = f_*creg[it] + i_*g_;
        float h  = o_*tanhq(cn);
        creg[it] = cn;
        hA[((j>>5)*64 + (r + 16*((j>>3)&3)))*8 + (j&7)] = f2bf(h);
        if (t == SEQ-1) {
          size_t bg = (size_t)blk*MB + r;
          out[LOGITS_N + bg*HID + j] = h;                          // h_n
          out[LOGITS_N + (size_t)BATCH*HID + bg*HID + j] = cn;     // c_n
        }
      }
    }
    __syncthreads();
  }

  // ---- epilogue: logits for t = SEQ-1 from final h (wave 3, tiles 8/9) ----
  if (w == 3) {
    f32x4 a1, a2;
    a1[0]=0.f; a1[1]=0.f; a1[2]=0.f; a1[3]=0.f;
    a2[0]=0.f; a2[1]=0.f; a2[2]=0.f; a2[3]=0.f;
    #pragma unroll
    for (int s = 0; s < KS; ++s) {
      s16x8 aF = *(const s16x8*)&hA[(s*64 + lane)*8];
      a1 = __builtin_amdgcn_mfma_f32_16x16x32_bf16(aF, wf[8][s], a1, 0, 0, 0);
      a2 = __builtin_amdgcn_mfma_f32_16x16x32_bf16(aF, wf[9][s], a2, 0, 0, 0);
    }
    if (lo) {
      #pragma unroll
      for (int q = 0; q < 4; ++q) {
        size_t bg = (size_t)blk*MB + rowq + q;
        size_t base = (bg*SEQ + (SEQ-1))*VOCAB;
        if (l15 < VOCAB)      out[base + l15]      = a1[q];
        if (16 + l15 < VOCAB) out[base + 16 + l15] = a2[q];
      }
    }
  }
}

extern "C" void kernel_launch(void* const* d_in, const int* in_sizes, int n_in,
                              void* d_out, int out_size, void* d_ws, size_t ws_size,
                              hipStream_t stream) {
  const int*   x     = (const int*)  d_in[0];
  const float* E     = (const float*)d_in[1];
  const float* W_ih  = (const float*)d_in[2];
  const float* W_hh  = (const float*)d_in[3];
  const float* b_ih  = (const float*)d_in[4];
  const float* b_hh  = (const float*)d_in[5];
  const float* W_out = (const float*)d_in[6];
  const float* b_out = (const float*)d_in[7];
  float* out = (float*)d_out;

  // ws layout: tbl 18*800*2 = 28800B | Wp 56*7*64*8*2 = 401408B   (~430KB)
  unsigned short* tbl = (unsigned short*)d_ws;
  short* Wp = (short*)d_ws + VOCAB*G4;

  int prep_threads = VOCAB*G4 + NT*KS*64;
  int prep_blocks  = (prep_threads + 255) / 256;
  prep_kernel<<<prep_blocks, 256, 0, stream>>>(E, W_ih, W_hh, b_ih, b_hh, W_out,
                                               b_out, tbl, Wp);
  lstm_kernel<<<BATCH/MB, TPB, 0, stream>>>(x, tbl, Wp, out);
}

// Round 7
// 446.773 us; speedup vs baseline: 1.7385x; 1.0448x over previous
//
#include <hip/hip_runtime.h>

// ---------------- problem constants ----------------
#define VOCAB 18
#define EMB   200
#define HID   200
#define G4    800           // 4*HID
#define SEQ   128
#define BATCH 2048
#define MB    8             // batch rows per block
#define NT    56            // N tiles of 16: 50 gate + 2 logit + 4 zero
#define KS    7             // K steps of 32 -> 224 padded K
                            // k<200: W_hh | k=200: bias row | k=201+v: tbl[v] row
#define TPB   256           // 4 waves -> 1 wave/SIMD -> 512-reg budget
#define TPW   14            // tiles per wave (56/4)
#define LOGITS_N ((size_t)BATCH*SEQ*VOCAB)

typedef short s16x8 __attribute__((ext_vector_type(8)));
typedef float f32x4 __attribute__((ext_vector_type(4)));

__device__ __forceinline__ unsigned short f2bf(float f) {
  unsigned int u = __float_as_uint(f);
  u += 0x7FFFu + ((u >> 16) & 1u);            // RNE; no NaNs in this problem
  return (unsigned short)(u >> 16);
}
__device__ __forceinline__ float sigm(float x) {
  float e = __builtin_amdgcn_exp2f(x * 1.4426950408889634f);
  return e * __builtin_amdgcn_rcpf(e + 1.0f);
}
__device__ __forceinline__ float tanhq(float x) {
  float e = __builtin_amdgcn_exp2f(x * 2.8853900817779268f); // exp2(2x*log2e)
  return 1.0f - 2.0f * __builtin_amdgcn_rcpf(e + 1.0f);
}

// one-hot / bias row position in hA (A-frag layout, s=6 K-block)
__device__ __forceinline__ int oh_elem(int r, int k) {
  return (384 + ((k >> 3) & 3) * 16 + r) * 8 + (k & 7);
}

// ---------------- prep 1: token table (gate-blocked cols, bf16 18x800) ------
// tbl[v][j] = (v!=0)*dot(E[v], W_ih[j]) + b_ih[j] + b_hh[j]
__global__ void prep_tbl(const float* __restrict__ E, const float* __restrict__ W_ih,
                         const float* __restrict__ b_ih, const float* __restrict__ b_hh,
                         unsigned short* __restrict__ tbl) {
  int tid = blockIdx.x * 256 + threadIdx.x;
  if (tid >= VOCAB * G4) return;
  int v = tid / G4, col = tid % G4;
  float s = b_ih[col] + b_hh[col];
  if (v != 0) {
    const float* Er = E + v * EMB;
    const float* Wr = W_ih + col * EMB;
    for (int e = 0; e < EMB; ++e) s += Er[e] * Wr[e];
  }
  tbl[tid] = f2bf(s);
}

// ---------------- prep 2: pack Wp (launched after prep_tbl; stream-ordered) --
// B-frag order: lane l elem i = B[32s+8*(l>>4)+i][16n+(l&15)]
//   B[k][col] = W_hh[col][k]        (col<800, k<200)
//             = W_out[col-800][k]   (800<=col<818, k<200)
//             = b_out[col-800]      (800<=col<818, k==200)
//             = tbl[k-201][col]     (col<800, 201<=k<219)   <- token rows
//             = 0 otherwise
__global__ void prep_wp(const float* __restrict__ W_hh, const float* __restrict__ W_out,
                        const float* __restrict__ b_out,
                        const unsigned short* __restrict__ tbl,
                        short* __restrict__ Wp) {
  int u = blockIdx.x * 256 + threadIdx.x;
  if (u >= NT * KS * 64) return;
  int n    = u / (KS * 64);
  int rem  = u % (KS * 64);
  int s_   = rem >> 6;
  int lane = rem & 63;
  int col  = 16 * n + (lane & 15);
  int kb   = lane >> 4;
  s16x8 o;
  #pragma unroll
  for (int i = 0; i < 8; ++i) {
    int k = 32 * s_ + 8 * kb + i;
    short b = 0;
    if (col < G4) {
      if (k < HID)                        b = (short)f2bf(W_hh[col * HID + k]);
      else if (k >= 201 && k < 201 + VOCAB) b = (short)tbl[(k - 201) * G4 + col];
    } else if (col < G4 + VOCAB) {
      if (k < HID)        b = (short)f2bf(W_out[(col - G4) * HID + k]);
      else if (k == HID)  b = (short)f2bf(b_out[col - G4]);
    }
    o[i] = b;
  }
  *(s16x8*)(Wp + (size_t)u * 8) = o;
}

// ---------------- main ----------------
// 256 blocks x 8 rows; 4 waves (1/SIMD), 392 weight AGPRs/wave pinned once.
// One MFMA sweep/t produces h@W_hh + tbl[x_t] + (logits+bias) via one-hot and
// bias K-rows. gatesL is col-major + bank-swizzled (b128 stores). aF held in
// regs across the 4 tile-groups (7 ds_read_b128/t).
__global__ __launch_bounds__(TPB) __attribute__((amdgpu_waves_per_eu(1, 1)))
void lstm_kernel(const int* __restrict__ x, const short* __restrict__ Wp,
                 float* __restrict__ out) {
  __shared__ unsigned short hA[KS * 64 * 8];   // A-frag layout bf16 (7.2KB)
  __shared__ float gatesL[G4 * 8];             // col-major [col][8], swizzled (25.6KB)
  __shared__ int   xtok[MB * SEQ];             // 4KB

  const int tid  = threadIdx.x;
  const int lane = tid & 63;
  const int w    = tid >> 6;                   // wave 0..3
  const int blk  = blockIdx.x;
  const int l15  = lane & 15;
  const int rowq = (lane >> 4) << 2;           // C rows rowq..rowq+3 (lanes<32 real)
  const bool lo  = (lane < 32);

  // h0 = 0; bf16 1.0 at bias row k=200 (elems 3200+8r)
  for (int i = tid; i < KS * 64 * 8; i += TPB)
    hA[i] = (i >= 3200 && i < 3264 && (i & 7) == 0) ? (unsigned short)0x3F80
                                                    : (unsigned short)0;
  for (int i = tid; i < MB * SEQ; i += TPB) xtok[i] = x[blk * (MB * SEQ) + i];

  // weight fragments: 14 tiles x 7 steps x 4 regs = 392 AGPRs, pinned once.
  s16x8 wf[TPW][KS];
  #pragma unroll
  for (int n = 0; n < TPW; ++n) {
    #pragma unroll
    for (int s = 0; s < KS; ++s) {
      wf[n][s] = *(const s16x8*)(Wp + ((((w * TPW + n) * KS) + s) * 64 + lane) * 8);
      asm volatile("" : "+a"(wf[n][s]));
    }
    asm volatile("" ::: "memory");
  }

  __syncthreads();
  // one-hot for t=0 (after barrier: hA zeroing done)
  if (tid < MB) hA[oh_elem(tid, 201 + xtok[tid * SEQ])] = 0x3F80;

  float creg[7] = {0.f, 0.f, 0.f, 0.f, 0.f, 0.f, 0.f};
  __syncthreads();

  #pragma unroll 1
  for (int t = 0; t < SEQ; ++t) {
    // ---- phase A: load aF once, 4 groups of 4 MFMA chains ----
    s16x8 aF[KS];
    #pragma unroll
    for (int s = 0; s < KS; ++s) aF[s] = *(const s16x8*)&hA[(s * 64 + lane) * 8];

    auto store_tile = [&](int n, const f32x4& a) {
      int col = 16 * (w * TPW + n) + l15;
      if (col < G4) {
        // col-major swizzled: elem = col*8 + (row ^ ((col>>2)&1)*4); rows rowq..+3
        *(f32x4*)&gatesL[col * 8 + (rowq ^ (l15 & 4))] = a;
      } else if (col < G4 + 32 && t > 0) {     // logits for step t-1 (bias baked)
        int v = col - G4;
        if (v < VOCAB) {
          #pragma unroll
          for (int q = 0; q < 4; ++q) {
            size_t bg = (size_t)blk * MB + rowq + q;
            out[(bg * SEQ + (t - 1)) * VOCAB + v] = a[q];
          }
        }
      }
    };

    #pragma unroll
    for (int g = 0; g < 4; ++g) {
      f32x4 acc[4];
      #pragma unroll
      for (int j = 0; j < 4; ++j) { acc[j][0]=0.f; acc[j][1]=0.f; acc[j][2]=0.f; acc[j][3]=0.f; }
      #pragma unroll
      for (int s = 0; s < KS; ++s) {
        #pragma unroll
        for (int j = 0; j < 4; ++j)
          if (4 * g + j < TPW)
            acc[j] = __builtin_amdgcn_mfma_f32_16x16x32_bf16(aF[s], wf[4 * g + j][s], acc[j], 0, 0, 0);
      }
      if (lo) {
        #pragma unroll
        for (int j = 0; j < 4; ++j)
          if (4 * g + j < TPW) store_tile(4 * g + j, acc[j]);
      }
    }
    __syncthreads();

    // ---- phase B: activations from gatesL (gates arrive complete), h -> hA ----
    #pragma unroll
    for (int it = 0; it < 7; ++it) {
      int p = tid + TPB * it;
      if (p < MB * HID) {
        int r = p / HID;
        int j = p - r * HID;
        int c0 = j, c1 = j + 200, c2 = j + 400, c3 = j + 600;
        float xi = gatesL[c0 * 8 + (r ^ ((c0 & 4)))];
        float xf = gatesL[c1 * 8 + (r ^ ((c1 & 4)))];
        float xg = gatesL[c2 * 8 + (r ^ ((c2 & 4)))];
        float xo = gatesL[c3 * 8 + (r ^ ((c3 & 4)))];
        float i_ = sigm(xi);
        float f_ = sigm(xf);
        float g_ = tanhq(xg);
        float o_ = sigm(xo);
        float cn = f_ * creg[it] + i_ * g_;
        float h  = o_ * tanhq(cn);
        creg[it] = cn;
        hA[((j >> 5) * 64 + (r + 16 * ((j >> 3) & 3))) * 8 + (j & 7)] = f2bf(h);
        if (t == SEQ - 1) {
          size_t bg = (size_t)blk * MB + r;
          out[LOGITS_N + bg * HID + j] = h;                          // h_n
          out[LOGITS_N + (size_t)BATCH * HID + bg * HID + j] = cn;   // c_n
        }
      }
    }
    // one-hot advance: clear x[t], set x[t+1] (same thread -> ordered)
    if (tid < MB && t + 1 < SEQ) {
      int v0 = xtok[tid * SEQ + t];
      int v1 = xtok[tid * SEQ + t + 1];
      hA[oh_elem(tid, 201 + v0)] = 0;
      hA[oh_elem(tid, 201 + v1)] = 0x3F80;
    }
    __syncthreads();
  }

  // ---- epilogue: logits for t = SEQ-1 (wave 3, tiles n=8,9; one-hot rows
  // hit zero B-cols for logit columns, so stale one-hot is harmless) ----
  if (w == 3) {
    s16x8 aF[KS];
    #pragma unroll
    for (int s = 0; s < KS; ++s) aF[s] = *(const s16x8*)&hA[(s * 64 + lane) * 8];
    f32x4 a1, a2;
    a1[0]=0.f; a1[1]=0.f; a1[2]=0.f; a1[3]=0.f;
    a2[0]=0.f; a2[1]=0.f; a2[2]=0.f; a2[3]=0.f;
    #pragma unroll
    for (int s = 0; s < KS; ++s) {
      a1 = __builtin_amdgcn_mfma_f32_16x16x32_bf16(aF[s], wf[8][s], a1, 0, 0, 0);
      a2 = __builtin_amdgcn_mfma_f32_16x16x32_bf16(aF[s], wf[9][s], a2, 0, 0, 0);
    }
    if (lo) {
      #pragma unroll
      for (int q = 0; q < 4; ++q) {
        size_t bg = (size_t)blk * MB + rowq + q;
        size_t base = (bg * SEQ + (SEQ - 1)) * VOCAB;
        if (l15 < VOCAB)      out[base + l15]      = a1[q];
        if (16 + l15 < VOCAB) out[base + 16 + l15] = a2[q];
      }
    }
  }
}

extern "C" void kernel_launch(void* const* d_in, const int* in_sizes, int n_in,
                              void* d_out, int out_size, void* d_ws, size_t ws_size,
                              hipStream_t stream) {
  const int*   x     = (const int*)  d_in[0];
  const float* E     = (const float*)d_in[1];
  const float* W_ih  = (const float*)d_in[2];
  const float* W_hh  = (const float*)d_in[3];
  const float* b_ih  = (const float*)d_in[4];
  const float* b_hh  = (const float*)d_in[5];
  const float* W_out = (const float*)d_in[6];
  const float* b_out = (const float*)d_in[7];
  float* out = (float*)d_out;

  // ws layout: tbl 18*800*2 = 28800B | Wp 56*7*64*8*2 = 401408B   (~430KB)
  unsigned short* tbl = (unsigned short*)d_ws;
  short* Wp = (short*)d_ws + VOCAB * G4;

  prep_tbl<<<(VOCAB * G4 + 255) / 256, 256, 0, stream>>>(E, W_ih, b_ih, b_hh, tbl);
  prep_wp<<<(NT * KS * 64 + 255) / 256, 256, 0, stream>>>(W_hh, W_out, b_out, tbl, Wp);
  lstm_kernel<<<BATCH / MB, TPB, 0, stream>>>(x, Wp, out);
}

// Round 8
// 343.483 us; speedup vs baseline: 2.2613x; 1.3007x over previous
//
#include <hip/hip_runtime.h>

// ---------------- problem constants ----------------
#define VOCAB 18
#define EMB   200
#define HID   200
#define G4    800           // 4*HID
#define SEQ   128
#define BATCH 2048
#define MB    8             // batch rows per block
#define NT    56            // N tiles of 16: 50 gate + 2 logit + 4 zero
#define KS    7             // K steps of 32 -> 224 padded K
                            // k<200: W_hh | k=200: bias row | k=201+v: tbl[v] row
#define TPB   256           // 4 waves -> 1 wave/SIMD -> 512-reg budget
#define TPW   14            // tiles per wave (56/4)
#define SV    (SEQ*VOCAB)   // 2304
#define LOGITS_N ((size_t)BATCH*SEQ*VOCAB)

typedef short s16x8 __attribute__((ext_vector_type(8)));
typedef short s16x4 __attribute__((ext_vector_type(4)));
typedef float f32x4 __attribute__((ext_vector_type(4)));

__device__ __forceinline__ unsigned short f2bf(float f) {
  unsigned int u = __float_as_uint(f);
  u += 0x7FFFu + ((u >> 16) & 1u);            // RNE; no NaNs in this problem
  return (unsigned short)(u >> 16);
}
__device__ __forceinline__ float sigm(float x) {
  float e = __builtin_amdgcn_exp2f(x * 1.4426950408889634f);
  return e * __builtin_amdgcn_rcpf(e + 1.0f);
}
__device__ __forceinline__ float tanhq(float x) {
  float e = __builtin_amdgcn_exp2f(x * 2.8853900817779268f); // exp2(2x*log2e)
  return 1.0f - 2.0f * __builtin_amdgcn_rcpf(e + 1.0f);
}

// one-hot / bias row position in hA (A-frag layout, s=6 K-block)
__device__ __forceinline__ int oh_elem(int r, int k) {
  return (384 + ((k >> 3) & 3) * 16 + r) * 8 + (k & 7);
}

// ---------------- prep 1: token table (bf16 18x800) ------
// tbl[v][j] = (v!=0)*dot(E[v], W_ih[j]) + b_ih[j] + b_hh[j]
__global__ void prep_tbl(const float* __restrict__ E, const float* __restrict__ W_ih,
                         const float* __restrict__ b_ih, const float* __restrict__ b_hh,
                         unsigned short* __restrict__ tbl) {
  int tid = blockIdx.x * 256 + threadIdx.x;
  if (tid >= VOCAB * G4) return;
  int v = tid / G4, col = tid % G4;
  float s = b_ih[col] + b_hh[col];
  if (v != 0) {
    const float* Er = E + v * EMB;
    const float* Wr = W_ih + col * EMB;
    for (int e = 0; e < EMB; ++e) s += Er[e] * Wr[e];
  }
  tbl[tid] = f2bf(s);
}

// ---------------- prep 2: pack Wp (after prep_tbl; stream-ordered) --
// B-frag order: lane l elem i = B[32s+8*(l>>4)+i][16n+(l&15)]
//   B[k][col] = W_hh[col][k]        (col<800, k<200)
//             = W_out[col-800][k]   (800<=col<818, k<200)
//             = b_out[col-800]      (800<=col<818, k==200)
//             = tbl[k-201][col]     (col<800, 201<=k<219)   <- token rows
//             = 0 otherwise
__global__ void prep_wp(const float* __restrict__ W_hh, const float* __restrict__ W_out,
                        const float* __restrict__ b_out,
                        const unsigned short* __restrict__ tbl,
                        short* __restrict__ Wp) {
  int u = blockIdx.x * 256 + threadIdx.x;
  if (u >= NT * KS * 64) return;
  int n    = u / (KS * 64);
  int rem  = u % (KS * 64);
  int s_   = rem >> 6;
  int lane = rem & 63;
  int col  = 16 * n + (lane & 15);
  int kb   = lane >> 4;
  s16x8 o;
  #pragma unroll
  for (int i = 0; i < 8; ++i) {
    int k = 32 * s_ + 8 * kb + i;
    short b = 0;
    if (col < G4) {
      if (k < HID)                          b = (short)f2bf(W_hh[col * HID + k]);
      else if (k >= 201 && k < 201 + VOCAB) b = (short)tbl[(k - 201) * G4 + col];
    } else if (col < G4 + VOCAB) {
      if (k < HID)        b = (short)f2bf(W_out[(col - G4) * HID + k]);
      else if (k == HID)  b = (short)f2bf(b_out[col - G4]);
    }
    o[i] = b;
  }
  *(s16x8*)(Wp + (size_t)u * 8) = o;
}

// ---------------- main ----------------
// 256 blocks x 8 rows; 4 waves (1/SIMD), 392 weight AGPRs/wave pinned once.
// Per step: one MFMA sweep (2 groups of 7 independent chains) -> gatesL
// (row-major, conflict-free) + logits -> LDS logL (no global stores in loop,
// so barriers don't drain vmcnt). Phase B: b128 gate reads, 4 elems/thread,
// b64 h write-back. Logits flushed coalesced at the end.
__global__ __launch_bounds__(TPB) __attribute__((amdgpu_waves_per_eu(1, 1)))
void lstm_kernel(const int* __restrict__ x, const short* __restrict__ Wp,
                 float* __restrict__ out) {
  __shared__ unsigned short hA[KS * 64 * 8];   // A-frag layout bf16 (7.2KB)
  __shared__ float gatesL[MB * G4];            // row-major [r][800] (25.6KB)
  __shared__ int   xtok[MB * SEQ];             // 4KB
  __shared__ float logL[MB * SV];              // [r][t][v] logits buffer (73.7KB)

  const int tid  = threadIdx.x;
  const int lane = tid & 63;
  const int w    = tid >> 6;                   // wave 0..3
  const int blk  = blockIdx.x;
  const int l15  = lane & 15;
  const int rowq = (lane >> 4) << 2;           // C rows rowq..rowq+3 (lanes<32 real)
  const bool lo  = (lane < 32);

  // h0 = 0; bf16 1.0 at bias row k=200 (elems 3200+8r)
  for (int i = tid; i < KS * 64 * 8; i += TPB)
    hA[i] = (i >= 3200 && i < 3264 && (i & 7) == 0) ? (unsigned short)0x3F80
                                                    : (unsigned short)0;
  for (int i = tid; i < MB * SEQ; i += TPB) xtok[i] = x[blk * (MB * SEQ) + i];

  // weight fragments: 14 tiles x 7 steps x 4 regs = 392 AGPRs, pinned once.
  s16x8 wf[TPW][KS];
  #pragma unroll
  for (int n = 0; n < TPW; ++n) {
    #pragma unroll
    for (int s = 0; s < KS; ++s) {
      wf[n][s] = *(const s16x8*)(Wp + ((((w * TPW + n) * KS) + s) * 64 + lane) * 8);
      asm volatile("" : "+a"(wf[n][s]));
    }
    asm volatile("" ::: "memory");
  }

  __syncthreads();
  // one-hot for t=0 (after barrier: hA zeroing done)
  if (tid < MB) hA[oh_elem(tid, 201 + xtok[tid * SEQ])] = 0x3F80;

  float cA[4] = {0.f, 0.f, 0.f, 0.f};          // c state (phase-B slot 0)
  float cB[4] = {0.f, 0.f, 0.f, 0.f};          // c state (phase-B slot 1)
  __syncthreads();

  #pragma unroll 1
  for (int t = 0; t < SEQ; ++t) {
    // ---- phase A: load aF once; 2 groups of 7 independent MFMA chains ----
    s16x8 aF[KS];
    #pragma unroll
    for (int s = 0; s < KS; ++s) aF[s] = *(const s16x8*)&hA[(s * 64 + lane) * 8];

    auto store_tile = [&](int n, const f32x4& a) {
      int col = 16 * (w * TPW + n) + l15;
      if (col < G4) {
        #pragma unroll
        for (int q = 0; q < 4; ++q)
          gatesL[(rowq + q) * G4 + col] = a[q];
      } else if (col < G4 + 32 && t > 0) {     // logits(t-1), bias baked in
        int v = col - G4;
        if (v < VOCAB) {
          #pragma unroll
          for (int q = 0; q < 4; ++q)
            logL[(rowq + q) * SV + (t - 1) * VOCAB + v] = a[q];
        }
      }
    };

    #pragma unroll
    for (int g = 0; g < 2; ++g) {
      f32x4 acc[7];
      #pragma unroll
      for (int j = 0; j < 7; ++j) { acc[j][0]=0.f; acc[j][1]=0.f; acc[j][2]=0.f; acc[j][3]=0.f; }
      #pragma unroll
      for (int s = 0; s < KS; ++s) {
        #pragma unroll
        for (int j = 0; j < 7; ++j)
          acc[j] = __builtin_amdgcn_mfma_f32_16x16x32_bf16(aF[s], wf[g * 7 + j][s], acc[j], 0, 0, 0);
      }
      if (lo) {
        #pragma unroll
        for (int j = 0; j < 7; ++j) store_tile(g * 7 + j, acc[j]);
      }
    }
    __syncthreads();

    // ---- phase B: 4 consecutive j per thread; b128 reads, b64 h write ----
    auto phaseB = [&](int pk, float (&cc)[4]) {
      int r  = pk / 50;                        // 50 packs of 4 per row
      int j0 = (pk - r * 50) * 4;
      f32x4 xi = *(const f32x4*)&gatesL[r * G4 + j0];
      f32x4 xf = *(const f32x4*)&gatesL[r * G4 + 200 + j0];
      f32x4 xg = *(const f32x4*)&gatesL[r * G4 + 400 + j0];
      f32x4 xo = *(const f32x4*)&gatesL[r * G4 + 600 + j0];
      s16x4 hp;
      f32x4 hv, cv;
      #pragma unroll
      for (int e = 0; e < 4; ++e) {
        float i_ = sigm(xi[e]);
        float f_ = sigm(xf[e]);
        float g_ = tanhq(xg[e]);
        float o_ = sigm(xo[e]);
        float cn = f_ * cc[e] + i_ * g_;
        float h  = o_ * tanhq(cn);
        cc[e] = cn;
        hp[e] = (short)f2bf(h);
        hv[e] = h; cv[e] = cn;
      }
      // 4 consecutive bf16 slots in hA (j0 % 4 == 0 guarantees contiguity)
      int hbase = ((j0 >> 5) * 64 + r + 16 * ((j0 >> 3) & 3)) * 8 + (j0 & 7);
      *(s16x4*)&hA[hbase] = hp;
      if (t == SEQ - 1) {
        size_t bg = (size_t)blk * MB + r;
        *(f32x4*)&out[LOGITS_N + bg * HID + j0] = hv;                        // h_n
        *(f32x4*)&out[LOGITS_N + (size_t)BATCH * HID + bg * HID + j0] = cv;  // c_n
      }
    };
    phaseB(tid, cA);
    if (tid < 144) phaseB(tid + 256, cB);      // packs 256..399

    // one-hot advance: clear x[t], set x[t+1] (same thread -> ordered)
    if (tid < MB && t + 1 < SEQ) {
      int v0 = xtok[tid * SEQ + t];
      int v1 = xtok[tid * SEQ + t + 1];
      hA[oh_elem(tid, 201 + v0)] = 0;
      hA[oh_elem(tid, 201 + v1)] = 0x3F80;
    }
    __syncthreads();
  }

  // ---- epilogue: logits for t = SEQ-1 (wave 3, tiles n=8,9 -> cols 800..831;
  // stale one-hot rows hit zeroed B-cols there, harmless) ----
  if (w == 3) {
    s16x8 aF[KS];
    #pragma unroll
    for (int s = 0; s < KS; ++s) aF[s] = *(const s16x8*)&hA[(s * 64 + lane) * 8];
    f32x4 a1, a2;
    a1[0]=0.f; a1[1]=0.f; a1[2]=0.f; a1[3]=0.f;
    a2[0]=0.f; a2[1]=0.f; a2[2]=0.f; a2[3]=0.f;
    #pragma unroll
    for (int s = 0; s < KS; ++s) {
      a1 = __builtin_amdgcn_mfma_f32_16x16x32_bf16(aF[s], wf[8][s], a1, 0, 0, 0);
      a2 = __builtin_amdgcn_mfma_f32_16x16x32_bf16(aF[s], wf[9][s], a2, 0, 0, 0);
    }
    if (lo) {
      #pragma unroll
      for (int q = 0; q < 4; ++q) {
        int base = (rowq + q) * SV + (SEQ - 1) * VOCAB;
        if (l15 < VOCAB)      logL[base + l15]      = a1[q];
        if (16 + l15 < VOCAB) logL[base + 16 + l15] = a2[q];
      }
    }
  }
  __syncthreads();

  // ---- flush logits: block's region is contiguous [blk*8 rows][128][18] ----
  float* dst = out + (size_t)blk * (MB * SV);
  for (int i = tid * 4; i < MB * SV; i += TPB * 4)
    *(f32x4*)&dst[i] = *(const f32x4*)&logL[i];
}

extern "C" void kernel_launch(void* const* d_in, const int* in_sizes, int n_in,
                              void* d_out, int out_size, void* d_ws, size_t ws_size,
                              hipStream_t stream) {
  const int*   x     = (const int*)  d_in[0];
  const float* E     = (const float*)d_in[1];
  const float* W_ih  = (const float*)d_in[2];
  const float* W_hh  = (const float*)d_in[3];
  const float* b_ih  = (const float*)d_in[4];
  const float* b_hh  = (const float*)d_in[5];
  const float* W_out = (const float*)d_in[6];
  const float* b_out = (const float*)d_in[7];
  float* out = (float*)d_out;

  // ws layout: tbl 18*800*2 = 28800B | Wp 56*7*64*8*2 = 401408B   (~430KB)
  unsigned short* tbl = (unsigned short*)d_ws;
  short* Wp = (short*)d_ws + VOCAB * G4;

  prep_tbl<<<(VOCAB * G4 + 255) / 256, 256, 0, stream>>>(E, W_ih, b_ih, b_hh, tbl);
  prep_wp<<<(NT * KS * 64 + 255) / 256, 256, 0, stream>>>(W_hh, W_out, b_out, tbl, Wp);
  lstm_kernel<<<BATCH / MB, TPB, 0, stream>>>(x, Wp, out);
}

// Round 9
// 342.890 us; speedup vs baseline: 2.2652x; 1.0017x over previous
//
#include <hip/hip_runtime.h>

// ---------------- problem constants ----------------
#define VOCAB 18
#define EMB   200
#define HID   200
#define G4    800           // 4*HID
#define SEQ   128
#define BATCH 2048
#define MB    8             // batch rows per block
#define NT    56            // N tiles of 16: 50 gate + 2 logit + 4 zero
#define KS    7             // K steps of 32 -> 224 padded K
                            // k<200: W_hh | k=200: bias row | k=201+v: tbl[v] row
#define TPB   512           // 8 waves -> 2 waves/SIMD (TLP!), 256-reg budget
#define TPW   7             // tiles per wave (56/8) -> 196 pinned AGPRs
#define SV    (SEQ*VOCAB)   // 2304
#define LOGITS_N ((size_t)BATCH*SEQ*VOCAB)

typedef short s16x8 __attribute__((ext_vector_type(8)));
typedef short s16x4 __attribute__((ext_vector_type(4)));
typedef float f32x4 __attribute__((ext_vector_type(4)));

__device__ __forceinline__ unsigned short f2bf(float f) {
  unsigned int u = __float_as_uint(f);
  u += 0x7FFFu + ((u >> 16) & 1u);            // RNE; no NaNs in this problem
  return (unsigned short)(u >> 16);
}
__device__ __forceinline__ float sigm(float x) {
  float e = __builtin_amdgcn_exp2f(x * 1.4426950408889634f);
  return e * __builtin_amdgcn_rcpf(e + 1.0f);
}
__device__ __forceinline__ float tanhq(float x) {
  float e = __builtin_amdgcn_exp2f(x * 2.8853900817779268f); // exp2(2x*log2e)
  return 1.0f - 2.0f * __builtin_amdgcn_rcpf(e + 1.0f);
}

// one-hot / bias row position in hA (A-frag layout, s=6 K-block)
__device__ __forceinline__ int oh_elem(int r, int k) {
  return (384 + ((k >> 3) & 3) * 16 + r) * 8 + (k & 7);
}

// ---------------- prep 1: token table (bf16 18x800) ------
// tbl[v][j] = (v!=0)*dot(E[v], W_ih[j]) + b_ih[j] + b_hh[j]
__global__ void prep_tbl(const float* __restrict__ E, const float* __restrict__ W_ih,
                         const float* __restrict__ b_ih, const float* __restrict__ b_hh,
                         unsigned short* __restrict__ tbl) {
  int tid = blockIdx.x * 256 + threadIdx.x;
  if (tid >= VOCAB * G4) return;
  int v = tid / G4, col = tid % G4;
  float s = b_ih[col] + b_hh[col];
  if (v != 0) {
    const float* Er = E + v * EMB;
    const float* Wr = W_ih + col * EMB;
    for (int e = 0; e < EMB; ++e) s += Er[e] * Wr[e];
  }
  tbl[tid] = f2bf(s);
}

// ---------------- prep 2: pack Wp (after prep_tbl; stream-ordered) --
// B-frag order: lane l elem i = B[32s+8*(l>>4)+i][16n+(l&15)]
//   B[k][col] = W_hh[col][k]        (col<800, k<200)
//             = W_out[col-800][k]   (800<=col<818, k<200)
//             = b_out[col-800]      (800<=col<818, k==200)
//             = tbl[k-201][col]     (col<800, 201<=k<219)   <- token rows
//             = 0 otherwise
__global__ void prep_wp(const float* __restrict__ W_hh, const float* __restrict__ W_out,
                        const float* __restrict__ b_out,
                        const unsigned short* __restrict__ tbl,
                        short* __restrict__ Wp) {
  int u = blockIdx.x * 256 + threadIdx.x;
  if (u >= NT * KS * 64) return;
  int n    = u / (KS * 64);
  int rem  = u % (KS * 64);
  int s_   = rem >> 6;
  int lane = rem & 63;
  int col  = 16 * n + (lane & 15);
  int kb   = lane >> 4;
  s16x8 o;
  #pragma unroll
  for (int i = 0; i < 8; ++i) {
    int k = 32 * s_ + 8 * kb + i;
    short b = 0;
    if (col < G4) {
      if (k < HID)                          b = (short)f2bf(W_hh[col * HID + k]);
      else if (k >= 201 && k < 201 + VOCAB) b = (short)tbl[(k - 201) * G4 + col];
    } else if (col < G4 + VOCAB) {
      if (k < HID)        b = (short)f2bf(W_out[(col - G4) * HID + k]);
      else if (k == HID)  b = (short)f2bf(b_out[col - G4]);
    }
    o[i] = b;
  }
  *(s16x8*)(Wp + (size_t)u * 8) = o;
}

// ---------------- main ----------------
// 256 blocks x 8 rows; 8 waves (2/SIMD -> latency hiding), 196 pinned weight
// AGPRs/wave. Fenced prologue keeps arch demand low so accum_offset ~60 and
// the AGPR partition fits (R5's failure mode). Phase A: 2 groups (4+3 tiles),
// acc live <= 16. One MFMA sweep/t makes gates + tbl[x_t] (one-hot rows) +
// logits (bias row). No global stores in loop. Phase B: 1 pack of 4/thread.
__global__ __launch_bounds__(TPB) __attribute__((amdgpu_waves_per_eu(2, 2)))
void lstm_kernel(const int* __restrict__ x, const short* __restrict__ Wp,
                 float* __restrict__ out) {
  __shared__ unsigned short hA[KS * 64 * 8];   // A-frag layout bf16 (7.2KB)
  __shared__ float gatesL[MB * G4];            // row-major [r][800] (25.6KB)
  __shared__ int   xtok[MB * SEQ];             // 4KB
  __shared__ float logL[MB * SV];              // [r][t][v] logits buffer (73.7KB)

  const int tid  = threadIdx.x;
  const int lane = tid & 63;
  const int w    = tid >> 6;                   // wave 0..7
  const int blk  = blockIdx.x;
  const int l15  = lane & 15;
  const int rowq = (lane >> 4) << 2;           // C rows rowq..rowq+3 (lanes<32 real)
  const bool lo  = (lane < 32);

  // h0 = 0; bf16 1.0 at bias row k=200 (elems 3200+8r)
  for (int i = tid; i < KS * 64 * 8; i += TPB)
    hA[i] = (i >= 3200 && i < 3264 && (i & 7) == 0) ? (unsigned short)0x3F80
                                                    : (unsigned short)0;
  for (int i = tid; i < MB * SEQ; i += TPB) xtok[i] = x[blk * (MB * SEQ) + i];

  // weight fragments: 7 tiles x 7 steps x 4 regs = 196 AGPRs, pinned once.
  // fence per tile bounds in-flight arch regs to 28 -> accum_offset stays low.
  s16x8 wf[TPW][KS];
  #pragma unroll
  for (int n = 0; n < TPW; ++n) {
    #pragma unroll
    for (int s = 0; s < KS; ++s) {
      wf[n][s] = *(const s16x8*)(Wp + ((((w * TPW + n) * KS) + s) * 64 + lane) * 8);
      asm volatile("" : "+a"(wf[n][s]));
    }
    asm volatile("" ::: "memory");
  }

  __syncthreads();
  // one-hot for t=0 (after barrier: hA zeroing done)
  if (tid < MB) hA[oh_elem(tid, 201 + xtok[tid * SEQ])] = 0x3F80;

  float creg[4] = {0.f, 0.f, 0.f, 0.f};        // c state: 1 pack of 4 per thread
  __syncthreads();

  #pragma unroll 1
  for (int t = 0; t < SEQ; ++t) {
    // ---- phase A: 2 groups (4+3 tiles); aF re-read per group ----
    auto store_tile = [&](int n, const f32x4& a) {
      int col = 16 * (w * TPW + n) + l15;
      if (col < G4) {
        #pragma unroll
        for (int q = 0; q < 4; ++q)
          gatesL[(rowq + q) * G4 + col] = a[q];
      } else if (col < G4 + 32 && t > 0) {     // logits(t-1), bias baked in
        int v = col - G4;
        if (v < VOCAB) {
          #pragma unroll
          for (int q = 0; q < 4; ++q)
            logL[(rowq + q) * SV + (t - 1) * VOCAB + v] = a[q];
        }
      }
    };

    {   // group 0: tiles 0..3
      f32x4 acc[4];
      #pragma unroll
      for (int j = 0; j < 4; ++j) { acc[j][0]=0.f; acc[j][1]=0.f; acc[j][2]=0.f; acc[j][3]=0.f; }
      #pragma unroll
      for (int s = 0; s < KS; ++s) {
        s16x8 aF = *(const s16x8*)&hA[(s * 64 + lane) * 8];
        #pragma unroll
        for (int j = 0; j < 4; ++j)
          acc[j] = __builtin_amdgcn_mfma_f32_16x16x32_bf16(aF, wf[j][s], acc[j], 0, 0, 0);
      }
      if (lo) {
        #pragma unroll
        for (int j = 0; j < 4; ++j) store_tile(j, acc[j]);
      }
    }
    {   // group 1: tiles 4..6
      f32x4 acc[3];
      #pragma unroll
      for (int j = 0; j < 3; ++j) { acc[j][0]=0.f; acc[j][1]=0.f; acc[j][2]=0.f; acc[j][3]=0.f; }
      #pragma unroll
      for (int s = 0; s < KS; ++s) {
        s16x8 aF = *(const s16x8*)&hA[(s * 64 + lane) * 8];
        #pragma unroll
        for (int j = 0; j < 3; ++j)
          acc[j] = __builtin_amdgcn_mfma_f32_16x16x32_bf16(aF, wf[4 + j][s], acc[j], 0, 0, 0);
      }
      if (lo) {
        #pragma unroll
        for (int j = 0; j < 3; ++j) store_tile(4 + j, acc[j]);
      }
    }
    __syncthreads();

    // ---- phase B: 1 pack of 4 consecutive j per thread (400 packs) ----
    if (tid < 400) {
      int r  = tid / 50;                       // 50 packs of 4 per row
      int j0 = (tid - r * 50) * 4;
      f32x4 xi = *(const f32x4*)&gatesL[r * G4 + j0];
      f32x4 xf = *(const f32x4*)&gatesL[r * G4 + 200 + j0];
      f32x4 xg = *(const f32x4*)&gatesL[r * G4 + 400 + j0];
      f32x4 xo = *(const f32x4*)&gatesL[r * G4 + 600 + j0];
      s16x4 hp;
      f32x4 hv, cv;
      #pragma unroll
      for (int e = 0; e < 4; ++e) {
        float i_ = sigm(xi[e]);
        float f_ = sigm(xf[e]);
        float g_ = tanhq(xg[e]);
        float o_ = sigm(xo[e]);
        float cn = f_ * creg[e] + i_ * g_;
        float h  = o_ * tanhq(cn);
        creg[e] = cn;
        hp[e] = (short)f2bf(h);
        hv[e] = h; cv[e] = cn;
      }
      int hbase = ((j0 >> 5) * 64 + r + 16 * ((j0 >> 3) & 3)) * 8 + (j0 & 7);
      *(s16x4*)&hA[hbase] = hp;
      if (t == SEQ - 1) {
        size_t bg = (size_t)blk * MB + r;
        *(f32x4*)&out[LOGITS_N + bg * HID + j0] = hv;                        // h_n
        *(f32x4*)&out[LOGITS_N + (size_t)BATCH * HID + bg * HID + j0] = cv;  // c_n
      }
    }
    // one-hot advance: clear x[t], set x[t+1] (same thread -> ordered)
    if (tid < MB && t + 1 < SEQ) {
      int v0 = xtok[tid * SEQ + t];
      int v1 = xtok[tid * SEQ + t + 1];
      hA[oh_elem(tid, 201 + v0)] = 0;
      hA[oh_elem(tid, 201 + v1)] = 0x3F80;
    }
    __syncthreads();
  }

  // ---- epilogue: logits for t = SEQ-1 (wave 7 owns tiles 50,51 = wf[1],wf[2];
  // stale one-hot rows hit zeroed B-cols for logit columns, harmless) ----
  if (w == 7) {
    s16x8 aF[KS];
    #pragma unroll
    for (int s = 0; s < KS; ++s) aF[s] = *(const s16x8*)&hA[(s * 64 + lane) * 8];
    f32x4 a1, a2;
    a1[0]=0.f; a1[1]=0.f; a1[2]=0.f; a1[3]=0.f;
    a2[0]=0.f; a2[1]=0.f; a2[2]=0.f; a2[3]=0.f;
    #pragma unroll
    for (int s = 0; s < KS; ++s) {
      a1 = __builtin_amdgcn_mfma_f32_16x16x32_bf16(aF[s], wf[1][s], a1, 0, 0, 0);
      a2 = __builtin_amdgcn_mfma_f32_16x16x32_bf16(aF[s], wf[2][s], a2, 0, 0, 0);
    }
    if (lo) {
      #pragma unroll
      for (int q = 0; q < 4; ++q) {
        int base = (rowq + q) * SV + (SEQ - 1) * VOCAB;
        if (l15 < VOCAB)      logL[base + l15]      = a1[q];
        if (16 + l15 < VOCAB) logL[base + 16 + l15] = a2[q];
      }
    }
  }
  __syncthreads();

  // ---- flush logits: block's region is contiguous [blk*8 rows][128][18] ----
  float* dst = out + (size_t)blk * (MB * SV);
  for (int i = tid * 4; i < MB * SV; i += TPB * 4)
    *(f32x4*)&dst[i] = *(const f32x4*)&logL[i];
}

extern "C" void kernel_launch(void* const* d_in, const int* in_sizes, int n_in,
                              void* d_out, int out_size, void* d_ws, size_t ws_size,
                              hipStream_t stream) {
  const int*   x     = (const int*)  d_in[0];
  const float* E     = (const float*)d_in[1];
  const float* W_ih  = (const float*)d_in[2];
  const float* W_hh  = (const float*)d_in[3];
  const float* b_ih  = (const float*)d_in[4];
  const float* b_hh  = (const float*)d_in[5];
  const float* W_out = (const float*)d_in[6];
  const float* b_out = (const float*)d_in[7];
  float* out = (float*)d_out;

  // ws layout: tbl 18*800*2 = 28800B | Wp 56*7*64*8*2 = 401408B   (~430KB)
  unsigned short* tbl = (unsigned short*)d_ws;
  short* Wp = (short*)d_ws + VOCAB * G4;

  prep_tbl<<<(VOCAB * G4 + 255) / 256, 256, 0, stream>>>(E, W_ih, b_ih, b_hh, tbl);
  prep_wp<<<(NT * KS * 64 + 255) / 256, 256, 0, stream>>>(W_hh, W_out, b_out, tbl, Wp);
  lstm_kernel<<<BATCH / MB, TPB, 0, stream>>>(x, Wp, out);
}